// Round 6
// baseline (251.989 us; speedup 1.0000x reference)
//
#include <hip/hip_runtime.h>
#include <math.h>
#include <stdint.h>

#define D_DIM 128
#define SEQ 2048
#define NHEADS 32
#define BC 64
#define SCALE 0.08838834764831843f  // 1/sqrt(128)
#define IMG_U16 24576               // per-(h,jt) tile image: Khi 8192 | Klo 8192 | Vhi 8192 u16

typedef short bf16x8 __attribute__((ext_vector_type(8)));
typedef float f32x4 __attribute__((ext_vector_type(4)));

union Frag { uint32_t u[4]; bf16x8 v; unsigned short s[8]; };
union Pack8 { unsigned short s[8]; uint4 q; };

__device__ __forceinline__ uint32_t fbits(float x) { return __builtin_bit_cast(uint32_t, x); }
__device__ __forceinline__ float bbits(uint32_t u) { return __builtin_bit_cast(float, u); }
__device__ __forceinline__ unsigned short bf16_rne(float x) {
    uint32_t u = fbits(x);
    u += 0x7FFFu + ((u >> 16) & 1u);
    return (unsigned short)(u >> 16);
}
// hi = truncate-to-bf16(x) (exact residual), lo = bf16(x - hi). even->low16, odd->high16.
__device__ __forceinline__ void split2(float a, float b, uint32_t& hp, uint32_t& lp) {
    uint32_t ua = fbits(a) & 0xFFFF0000u, ub = fbits(b) & 0xFFFF0000u;
    float la = a - bbits(ua), lb = b - bbits(ub);
    hp = (ua >> 16) | ub;
    lp = (fbits(la) >> 16) | (fbits(lb) & 0xFFFF0000u);
}

// async global->LDS, 16B per lane; lds base wave-uniform, lane*16 implicit.
__device__ __forceinline__ void gl_lds16(const unsigned short* g, unsigned short* l) {
    __builtin_amdgcn_global_load_lds(
        (const __attribute__((address_space(1))) uint32_t*)g,
        (__attribute__((address_space(3))) uint32_t*)l, 16, 0, 0);
}

// max over the 16-lane DPP row (lanes qd*16..qd*16+15) — pure VALU, no LDS.
__device__ __forceinline__ float dpp_max16(float x) {
    int y;
    y = __builtin_amdgcn_update_dpp(0, __builtin_bit_cast(int, x), 0xB1, 0xF, 0xF, true);   // quad_perm [1,0,3,2]
    x = fmaxf(x, __builtin_bit_cast(float, y));
    y = __builtin_amdgcn_update_dpp(0, __builtin_bit_cast(int, x), 0x4E, 0xF, 0xF, true);   // quad_perm [2,3,0,1]
    x = fmaxf(x, __builtin_bit_cast(float, y));
    y = __builtin_amdgcn_update_dpp(0, __builtin_bit_cast(int, x), 0x141, 0xF, 0xF, true);  // row_half_mirror
    x = fmaxf(x, __builtin_bit_cast(float, y));
    y = __builtin_amdgcn_update_dpp(0, __builtin_bit_cast(int, x), 0x140, 0xF, 0xF, true);  // row_mirror
    x = fmaxf(x, __builtin_bit_cast(float, y));
    return x;
}

// ---------------- pre-pass: build pre-swizzled LDS tile images in ws ----------------
// Khi[n*128 + ((kc8^(n&7))*8)] | Klo at +8192 | Vhi^T [d*64 + ((cc^(d&7))*8)] at +16384.
__global__ __launch_bounds__(256) void cvt_kv(
    const float* __restrict__ k, const float* __restrict__ v, unsigned short* __restrict__ ws)
{
    __shared__ float Ls[64 * 129];         // V tile, pad 129 -> 2-way-free column reads
    const int b = blockIdx.x;              // 1024 = 32 heads x 32 jt
    const int h = b >> 5, jt = b & 31;
    const int t = (int)threadIdx.x;
    unsigned short* img = ws + (size_t)b * IMG_U16;
    const float* kp = k + ((size_t)h * SEQ + jt * 64) * D_DIM;
    const float* vp = v + ((size_t)h * SEQ + jt * 64) * D_DIM;

    // V tile -> LDS (coalesced float4 reads)
    #pragma unroll
    for (int it = 0; it < 8; ++it) {
        int idx = it * 256 + t;
        int row = idx >> 5, c4 = idx & 31;
        float4 e = *(const float4*)(vp + (size_t)row * D_DIM + c4 * 4);
        float* lp = Ls + row * 129 + c4 * 4;
        lp[0] = e.x; lp[1] = e.y; lp[2] = e.z; lp[3] = e.w;
    }
    // K: hi/lo split, coalesced reads, swizzled-image writes
    #pragma unroll
    for (int u = 0; u < 4; ++u) {
        int idx = u * 256 + t;
        int n = idx >> 4, kc8 = idx & 15;
        float e[8];
        *(float4*)(e)     = *(const float4*)(kp + (size_t)n * D_DIM + kc8 * 8);
        *(float4*)(e + 4) = *(const float4*)(kp + (size_t)n * D_DIM + kc8 * 8 + 4);
        uint32_t hp[4], lp[4];
        #pragma unroll
        for (int j = 0; j < 4; ++j) split2(e[2 * j], e[2 * j + 1], hp[j], lp[j]);
        int off = n * 128 + ((kc8 ^ (n & 7)) * 8);
        *(uint4*)(img + off)        = make_uint4(hp[0], hp[1], hp[2], hp[3]);
        *(uint4*)(img + 8192 + off) = make_uint4(lp[0], lp[1], lp[2], lp[3]);
    }
    __syncthreads();
    // V^T from LDS columns -> bf16 RNE, swizzled-image writes
    #pragma unroll
    for (int u = 0; u < 4; ++u) {
        int idx = u * 256 + t;
        int d = idx >> 3, cc = idx & 7;
        Pack8 p8;
        #pragma unroll
        for (int j = 0; j < 8; ++j)
            p8.s[j] = bf16_rne(Ls[(cc * 8 + j) * 129 + d]);
        *(uint4*)(img + 16384 + d * 64 + ((cc ^ (d & 7)) * 8)) = p8.q;
    }
}

// ---------------- attention: 256 thr = 4 waves x 32 q-rows; single-stage DMA, 2 blocks/CU ----------------
// 16x16x32 bf16 MFMA; layouts: A[m=lane&15][k=quad*8+j], B[k=quad*8+j][n=lane&15],
// C/D[row=quad*4+reg][col=lane&15].
__global__ __launch_bounds__(256, 2) void fa_fwd4(
    const float* __restrict__ q, const unsigned short* __restrict__ ws, float* __restrict__ out)
{
    __shared__ __align__(16) unsigned short Stage[IMG_U16];   // 48KB: Khi|Klo|Vhi
    __shared__ __align__(16) unsigned short Pbs[128 * 64];    // 16KB -> 64KB total, 2 blocks/CU

    // Complementary pairing: blocks x and x+256 share a CU (round-robin fill),
    // it(x) + it(x+256) = 15 -> every CU does exactly 34 tile-iters.
    const int x = blockIdx.x;
    const int h = x & 31;
    const int s = (x >> 5) & 7;
    const int it = (x < 256) ? (15 - s) : s;

    const int t    = (int)threadIdx.x;
    const int wb   = t >> 6;
    const int lane = t & 63;
    const int ln   = lane & 15;
    const int qd   = lane >> 4;

    const unsigned short* wsh = ws + (size_t)(h * 32) * IMG_U16;
    float* out_o = out;
    float* out_m = out + (size_t)NHEADS * SEQ * D_DIM;
    float* out_l = out_m + (size_t)NHEADS * SEQ * 8;

    const int qrow0 = it * 128 + wb * 32;

    // Q fragments (exact hi/lo split), 2 m-tiles: 64 VGPRs
    Frag Qh[2][4], Ql[2][4];
    #pragma unroll
    for (int mt = 0; mt < 2; ++mt) {
        const float* qp = q + ((size_t)h * SEQ + qrow0 + mt * 16 + ln) * D_DIM;
        #pragma unroll
        for (int kc = 0; kc < 4; ++kc) {
            const int kb = kc * 32 + qd * 8;
            float e[8];
            *(float4*)(e)     = *(const float4*)(qp + kb);
            *(float4*)(e + 4) = *(const float4*)(qp + kb + 4);
            #pragma unroll
            for (int j = 0; j < 4; ++j)
                split2(e[2 * j], e[2 * j + 1], Qh[mt][kc].u[j], Ql[mt][kc].u[j]);
        }
    }

    Frag Ones;  // all-ones bf16 B-frag: row-sum via MFMA (l accumulator)
    #pragma unroll
    for (int j = 0; j < 4; ++j) Ones.u[j] = 0x3F803F80u;

    f32x4 accO[2][8], accL[2];
    float m_r[2][4];
    #pragma unroll
    for (int mt = 0; mt < 2; ++mt) {
        #pragma unroll
        for (int nd = 0; nd < 8; ++nd) accO[mt][nd] = (f32x4){0.f, 0.f, 0.f, 0.f};
        accL[mt] = (f32x4){0.f, 0.f, 0.f, 0.f};
        #pragma unroll
        for (int r = 0; r < 4; ++r) m_r[mt][r] = -INFINITY;
    }

    const int jt_end = 2 * it + 1;
    for (int jt = 0; jt <= jt_end; ++jt) {
        const int c0 = jt * BC;
        __syncthreads();  // prev tile's Stage reads done -> safe to overwrite

        {   // DMA this tile: 12 x 1KB per wave, all in flight
            const unsigned short* g = wsh + (size_t)jt * IMG_U16 + wb * 6144 + lane * 8;
            unsigned short* l = &Stage[wb * 6144];
            #pragma unroll
            for (int i = 0; i < 12; ++i) gl_lds16(g + i * 512, l + i * 512);
        }
        __syncthreads();  // drain (syncthreads implies vmcnt(0))

        const unsigned short* Khs = Stage;
        const unsigned short* Kls = Stage + 8192;
        const unsigned short* Vhs = Stage + 16384;

        if (c0 <= qrow0 + 31) {  // wave-uniform causal skip
            // ---- S = Q K^T (split-3: hh + hl + lh), 96 MFMAs ----
            f32x4 accS[2][4];
            #pragma unroll
            for (int mt = 0; mt < 2; ++mt)
                #pragma unroll
                for (int nt = 0; nt < 4; ++nt) accS[mt][nt] = (f32x4){0.f, 0.f, 0.f, 0.f};
            #pragma unroll
            for (int kc = 0; kc < 4; ++kc) {
                #pragma unroll
                for (int nt = 0; nt < 4; ++nt) {
                    int n = nt * 16 + ln;
                    int off = n * 128 + (((kc * 4 + qd) ^ (n & 7)) * 8);
                    Frag Bh, Bl;
                    Bh.v = *(const bf16x8*)(Khs + off);
                    Bl.v = *(const bf16x8*)(Kls + off);
                    #pragma unroll
                    for (int mt = 0; mt < 2; ++mt) {
                        f32x4 c = accS[mt][nt];
                        c = __builtin_amdgcn_mfma_f32_16x16x32_bf16(Qh[mt][kc].v, Bh.v, c, 0, 0, 0);
                        c = __builtin_amdgcn_mfma_f32_16x16x32_bf16(Qh[mt][kc].v, Bl.v, c, 0, 0, 0);
                        c = __builtin_amdgcn_mfma_f32_16x16x32_bf16(Ql[mt][kc].v, Bh.v, c, 0, 0, 0);
                        accS[mt][nt] = c;
                    }
                }
            }
            // ---- online softmax: max via DPP (VALU), sum via ones-MFMA below ----
            #pragma unroll
            for (int mt = 0; mt < 2; ++mt) {
                #pragma unroll
                for (int r = 0; r < 4; ++r) {
                    const int rowg = qrow0 + mt * 16 + qd * 4 + r;
                    float sv[4], mx = -INFINITY;
                    #pragma unroll
                    for (int nt = 0; nt < 4; ++nt) {
                        float sc = accS[mt][nt][r] * SCALE;
                        if (c0 + nt * 16 + ln > rowg) sc = -INFINITY;  // causal
                        sv[nt] = sc; mx = fmaxf(mx, sc);
                    }
                    mx = dpp_max16(mx);
                    const float mnew = fmaxf(m_r[mt][r], mx);
                    const float alpha = __expf(m_r[mt][r] - mnew);  // first tile: exp(-inf)=0
                    m_r[mt][r] = mnew;
                    accL[mt][r] *= alpha;
                    #pragma unroll
                    for (int nd = 0; nd < 8; ++nd) accO[mt][nd][r] *= alpha;
                    const int R = wb * 32 + mt * 16 + qd * 4 + r;  // intra-wave P region
                    #pragma unroll
                    for (int nt = 0; nt < 4; ++nt) {
                        int c = nt * 16 + ln;
                        Pbs[R * 64 + (((c >> 3) ^ (R & 7)) * 8) + (c & 7)] = bf16_rne(__expf(sv[nt] - mnew));
                    }
                }
            }
            // ---- O += P V_hi; l += P . 1  (36 MFMAs) ----
            #pragma unroll
            for (int kc2 = 0; kc2 < 2; ++kc2) {
                Frag Pf[2];
                #pragma unroll
                for (int mt = 0; mt < 2; ++mt) {
                    const int R = wb * 32 + mt * 16 + ln;
                    Pf[mt].v = *(const bf16x8*)(Pbs + R * 64 + (((kc2 * 4 + qd) ^ (R & 7)) * 8));
                    accL[mt] = __builtin_amdgcn_mfma_f32_16x16x32_bf16(Pf[mt].v, Ones.v, accL[mt], 0, 0, 0);
                }
                #pragma unroll
                for (int nd = 0; nd < 8; ++nd) {
                    int dcol = nd * 16 + ln;
                    Frag Vh2;
                    Vh2.v = *(const bf16x8*)(Vhs + dcol * 64 + (((kc2 * 4 + qd) ^ (dcol & 7)) * 8));
                    #pragma unroll
                    for (int mt = 0; mt < 2; ++mt)
                        accO[mt][nd] = __builtin_amdgcn_mfma_f32_16x16x32_bf16(Pf[mt].v, Vh2.v, accO[mt][nd], 0, 0, 0);
                }
            }
        }
    }

    // ---- epilogue: O/l, stats tiled x8 ----
    #pragma unroll
    for (int mt = 0; mt < 2; ++mt) {
        #pragma unroll
        for (int r = 0; r < 4; ++r) {
            const int rowg = qrow0 + mt * 16 + qd * 4 + r;
            const float lv = accL[mt][r];
            const float invl = 1.0f / lv;
            float* op = out_o + (size_t)h * SEQ * D_DIM + (size_t)rowg * D_DIM;
            #pragma unroll
            for (int nd = 0; nd < 8; ++nd) op[nd * 16 + ln] = accO[mt][nd][r] * invl;
            if (ln < 8) {
                size_t sb = ((size_t)h * SEQ + rowg) * 8 + ln;
                out_m[sb] = m_r[mt][r];
                out_l[sb] = lv;
            }
        }
    }
}

// ---------------- fallback (proven R3/R4 kernel, used only if ws too small) ----------------
__global__ __launch_bounds__(256, 2) void fa_fwd_fb(
    const float* __restrict__ q, const float* __restrict__ k,
    const float* __restrict__ v, float* __restrict__ out)
{
    __shared__ __align__(16) unsigned short Khs[64 * 128];
    __shared__ __align__(16) unsigned short Kls[64 * 128];
    __shared__ __align__(16) unsigned short Vhs[128 * 64];
    __shared__ __align__(16) unsigned short Vls[128 * 64];
    __shared__ __align__(16) unsigned short Pbs[128 * 64];

    const int x = blockIdx.x;
    const int y = x >> 3;
    const int s_idx = y & 15;
    const int h = (x & 7) * 4 + (y >> 4);
    const int it = (y < 32) ? (15 - s_idx) : s_idx;

    const int t = (int)threadIdx.x;
    const int wb = t >> 6, lane = t & 63, ln = lane & 15, qd = lane >> 4;

    const float* qh = q + (size_t)h * SEQ * D_DIM;
    const float* kh = k + (size_t)h * SEQ * D_DIM;
    const float* vh = v + (size_t)h * SEQ * D_DIM;
    float* out_o = out;
    float* out_m = out + (size_t)NHEADS * SEQ * D_DIM;
    float* out_l = out_m + (size_t)NHEADS * SEQ * 8;

    const int qrow0 = it * 128 + wb * 32;

    Frag Qh[2][4], Ql[2][4];
    #pragma unroll
    for (int mt = 0; mt < 2; ++mt) {
        const float* qp = qh + (size_t)(qrow0 + mt * 16 + ln) * D_DIM;
        #pragma unroll
        for (int kc = 0; kc < 4; ++kc) {
            const int kb = kc * 32 + qd * 8;
            float e[8];
            *(float4*)(e)     = *(const float4*)(qp + kb);
            *(float4*)(e + 4) = *(const float4*)(qp + kb + 4);
            #pragma unroll
            for (int j = 0; j < 4; ++j)
                split2(e[2 * j], e[2 * j + 1], Qh[mt][kc].u[j], Ql[mt][kc].u[j]);
        }
    }

    f32x4 accO[2][8];
    float m_r[2][4], l_r[2][4];
    #pragma unroll
    for (int mt = 0; mt < 2; ++mt) {
        #pragma unroll
        for (int nd = 0; nd < 8; ++nd) accO[mt][nd] = (f32x4){0.f, 0.f, 0.f, 0.f};
        #pragma unroll
        for (int r = 0; r < 4; ++r) { m_r[mt][r] = -INFINITY; l_r[mt][r] = 0.f; }
    }

    const int jt_end = 2 * it + 1;
    for (int jt = 0; jt <= jt_end; ++jt) {
        const int c0 = jt * BC;
        __syncthreads();
        #pragma unroll
        for (int itr = 0; itr < 8; ++itr) {
            int f = itr * 256 + t;
            int row = f >> 5, d4 = f & 31;
            float e[4];
            *(float4*)e = *(const float4*)(kh + (size_t)(c0 + row) * D_DIM + d4 * 4);
            uint32_t hp[2], lp[2];
            split2(e[0], e[1], hp[0], lp[0]);
            split2(e[2], e[3], hp[1], lp[1]);
            int off = row * 128 + (((d4 >> 1) ^ (row & 7)) * 8) + (d4 & 1) * 4;
            *(uint2*)(Khs + off) = make_uint2(hp[0], hp[1]);
            *(uint2*)(Kls + off) = make_uint2(lp[0], lp[1]);
        }
        #pragma unroll
        for (int uu = 0; uu < 4; ++uu) {
            int ug = wb * 4 + uu;
            int cc = ug >> 1, dh = ug & 1;
            int d = dh * 64 + lane;
            Frag fh, fl;
            #pragma unroll
            for (int j = 0; j < 8; j += 2) {
                float a = vh[(size_t)(c0 + cc * 8 + j) * D_DIM + d];
                float b = vh[(size_t)(c0 + cc * 8 + j + 1) * D_DIM + d];
                split2(a, b, fh.u[j >> 1], fl.u[j >> 1]);
            }
            int off = d * 64 + ((cc ^ (d & 7)) * 8);
            *(bf16x8*)(Vhs + off) = fh.v;
            *(bf16x8*)(Vls + off) = fl.v;
        }
        __syncthreads();

        if (c0 <= qrow0 + 31) {
            f32x4 accS[2][4];
            #pragma unroll
            for (int mt = 0; mt < 2; ++mt)
                #pragma unroll
                for (int nt = 0; nt < 4; ++nt) accS[mt][nt] = (f32x4){0.f, 0.f, 0.f, 0.f};
            #pragma unroll
            for (int kc = 0; kc < 4; ++kc) {
                #pragma unroll
                for (int nt = 0; nt < 4; ++nt) {
                    int n = nt * 16 + ln;
                    int off = n * 128 + (((kc * 4 + qd) ^ (n & 7)) * 8);
                    Frag Bh, Bl;
                    Bh.v = *(const bf16x8*)(Khs + off);
                    Bl.v = *(const bf16x8*)(Kls + off);
                    #pragma unroll
                    for (int mt = 0; mt < 2; ++mt) {
                        f32x4 c = accS[mt][nt];
                        c = __builtin_amdgcn_mfma_f32_16x16x32_bf16(Qh[mt][kc].v, Bh.v, c, 0, 0, 0);
                        c = __builtin_amdgcn_mfma_f32_16x16x32_bf16(Qh[mt][kc].v, Bl.v, c, 0, 0, 0);
                        c = __builtin_amdgcn_mfma_f32_16x16x32_bf16(Ql[mt][kc].v, Bh.v, c, 0, 0, 0);
                        accS[mt][nt] = c;
                    }
                }
            }
            #pragma unroll
            for (int mt = 0; mt < 2; ++mt) {
                #pragma unroll
                for (int r = 0; r < 4; ++r) {
                    const int rowg = qrow0 + mt * 16 + qd * 4 + r;
                    float sv[4], mx = -INFINITY;
                    #pragma unroll
                    for (int nt = 0; nt < 4; ++nt) {
                        float sc = accS[mt][nt][r] * SCALE;
                        if (c0 + nt * 16 + ln > rowg) sc = -INFINITY;
                        sv[nt] = sc; mx = fmaxf(mx, sc);
                    }
                    #pragma unroll
                    for (int off = 1; off < 16; off <<= 1) mx = fmaxf(mx, __shfl_xor(mx, off));
                    const float mnew = fmaxf(m_r[mt][r], mx);
                    const float alpha = __expf(m_r[mt][r] - mnew);
                    float p[4], rs = 0.f;
                    #pragma unroll
                    for (int nt = 0; nt < 4; ++nt) { p[nt] = __expf(sv[nt] - mnew); rs += p[nt]; }
                    #pragma unroll
                    for (int off = 1; off < 16; off <<= 1) rs += __shfl_xor(rs, off);
                    m_r[mt][r] = mnew;
                    l_r[mt][r] = l_r[mt][r] * alpha + rs;
                    #pragma unroll
                    for (int nd = 0; nd < 8; ++nd) accO[mt][nd][r] *= alpha;
                    const int R = wb * 32 + mt * 16 + qd * 4 + r;
                    #pragma unroll
                    for (int nt = 0; nt < 4; ++nt) {
                        int c = nt * 16 + ln;
                        Pbs[R * 64 + (((c >> 3) ^ (R & 7)) * 8) + (c & 7)] = bf16_rne(p[nt]);
                    }
                }
            }
            #pragma unroll
            for (int kc2 = 0; kc2 < 2; ++kc2) {
                Frag Pf[2];
                #pragma unroll
                for (int mt = 0; mt < 2; ++mt) {
                    int R = wb * 32 + mt * 16 + ln;
                    Pf[mt].v = *(const bf16x8*)(Pbs + R * 64 + (((kc2 * 4 + qd) ^ (R & 7)) * 8));
                }
                #pragma unroll
                for (int nd = 0; nd < 8; ++nd) {
                    int dcol = nd * 16 + ln;
                    int voff = dcol * 64 + (((kc2 * 4 + qd) ^ (dcol & 7)) * 8);
                    Frag Vh2, Vl2;
                    Vh2.v = *(const bf16x8*)(Vhs + voff);
                    Vl2.v = *(const bf16x8*)(Vls + voff);
                    #pragma unroll
                    for (int mt = 0; mt < 2; ++mt) {
                        f32x4 c = accO[mt][nd];
                        c = __builtin_amdgcn_mfma_f32_16x16x32_bf16(Pf[mt].v, Vh2.v, c, 0, 0, 0);
                        c = __builtin_amdgcn_mfma_f32_16x16x32_bf16(Pf[mt].v, Vl2.v, c, 0, 0, 0);
                        accO[mt][nd] = c;
                    }
                }
            }
        }
    }

    #pragma unroll
    for (int mt = 0; mt < 2; ++mt) {
        #pragma unroll
        for (int r = 0; r < 4; ++r) {
            const int rowg = qrow0 + mt * 16 + qd * 4 + r;
            const float invl = 1.0f / l_r[mt][r];
            float* op = out_o + (size_t)h * SEQ * D_DIM + (size_t)rowg * D_DIM;
            #pragma unroll
            for (int nd = 0; nd < 8; ++nd) op[nd * 16 + ln] = accO[mt][nd][r] * invl;
            if (ln < 8) {
                size_t sb = ((size_t)h * SEQ + rowg) * 8 + ln;
                out_m[sb] = m_r[mt][r];
                out_l[sb] = l_r[mt][r];
            }
        }
    }
}

extern "C" void kernel_launch(void* const* d_in, const int* in_sizes, int n_in,
                              void* d_out, int out_size, void* d_ws, size_t ws_size,
                              hipStream_t stream) {
    const float* q = (const float*)d_in[0];
    const float* k = (const float*)d_in[1];
    const float* v = (const float*)d_in[2];
    float* out = (float*)d_out;

    const size_t need = (size_t)1024 * IMG_U16 * sizeof(unsigned short);  // 48 MB
    if (ws_size >= need) {
        unsigned short* ws = (unsigned short*)d_ws;
        cvt_kv<<<dim3(1024), dim3(256), 0, stream>>>(k, v, ws);
        fa_fwd4<<<dim3(512), dim3(256), 0, stream>>>(q, ws, out);
    } else {
        fa_fwd_fb<<<dim3(512), dim3(256), 0, stream>>>(q, k, v, out);
    }
}